// Round 14
// baseline (2785.288 us; speedup 1.0000x reference)
//
#include <hip/hip_runtime.h>
#include <hip/hip_fp16.h>

#define Bb 32
#define Ll 512
#define Dd 1024
#define Hh 256
#define Ee 64

__device__ __forceinline__ float sigmoidf_(float x) { return 1.f / (1.f + __expf(-x)); }
__device__ __forceinline__ float tanhf_(float x) { return 1.f - 2.f / (__expf(2.f * x) + 1.f); }

typedef _Float16 v8hf __attribute__((ext_vector_type(8)));
typedef float v4f __attribute__((ext_vector_type(4)));

__device__ __forceinline__ int sdot4_(unsigned int a, unsigned int b, int acc) {
#if __has_builtin(__builtin_amdgcn_sdot4)
  return __builtin_amdgcn_sdot4((int)a, (int)b, acc, false);
#else
  int r = acc;
#pragma unroll
  for (int i = 0; i < 4; i++)
    r += (((int)a << (24 - 8 * i)) >> 24) * (((int)b << (24 - 8 * i)) >> 24);
  return r;
#endif
}

// ---------------------------------------------------------------------------
// generic f32 -> f16 converter (8 elems/thread)
// ---------------------------------------------------------------------------
__global__ __launch_bounds__(256) void cvt_h(const float* __restrict__ s,
                                             __half* __restrict__ d, int n8) {
  const int i = blockIdx.x * 256 + threadIdx.x;
  if (i >= n8) return;
  const float4 a = ((const float4*)s)[2 * i];
  const float4 b = ((const float4*)s)[2 * i + 1];
  union { __half h[8]; uint4 u; } o;
  o.h[0] = __float2half(a.x); o.h[1] = __float2half(a.y);
  o.h[2] = __float2half(a.z); o.h[3] = __float2half(a.w);
  o.h[4] = __float2half(b.x); o.h[5] = __float2half(b.y);
  o.h[6] = __float2half(b.z); o.h[7] = __float2half(b.w);
  ((uint4*)d)[i] = o.u;
}

// ---------------------------------------------------------------------------
// W_hh -> int8, 16-k-chunk layout: WQ4[slice][ch(16)][row(1024)] uint4
// ---------------------------------------------------------------------------
__global__ __launch_bounds__(256) void conv_wq4(const float* __restrict__ src,
                                                uint4* __restrict__ dst) {
  const int s = blockIdx.y;
  const int idx = blockIdx.x * 256 + threadIdx.x;   // 0..16383
  const int row = idx & 1023;
  const int ch = idx >> 10;
  const float* sp = src + (size_t)s * 262144 + (size_t)row * 256 + ch * 16;
  unsigned int u[4];
#pragma unroll
  for (int g4 = 0; g4 < 4; ++g4) {
    const float4 v = *(const float4*)(sp + 4 * g4);
    const float vv[4] = {v.x, v.y, v.z, v.w};
    unsigned int packed = 0;
#pragma unroll
    for (int i = 0; i < 4; i++) {
      int q = (int)rintf(vv[i] * 2048.f);
      q = max(-127, min(127, q));
      packed |= ((unsigned int)(q & 0xFF)) << (8 * i);
    }
    u[g4] = packed;
  }
  dst[(size_t)s * 16384 + (size_t)ch * 1024 + row] = make_uint4(u[0], u[1], u[2], u[3]);
}

// ---------------------------------------------------------------------------
// MFMA f16 GEMM v2: 128x128 tile, 512 thr / 8 waves (2x4), padded LDS.
// ---------------------------------------------------------------------------
template <int DK, bool XL>
__global__ __launch_bounds__(512) void xg_gemm2(const __half* __restrict__ A,
                                                const __half* __restrict__ W,
                                                const float* __restrict__ bias,
                                                __half* __restrict__ xg) {
  const int dir = blockIdx.x >> 3;
  const int n0 = (blockIdx.x & 7) * 128;
  const int m0 = blockIdx.y * 128;
  const __half* Wd = W + (size_t)dir * (1024 * DK);
  const float* bd = bias + dir * 1024;
  __half* out = xg + (size_t)dir * (16384ull * 1024);

  __shared__ __align__(16) __half As[128][40];
  __shared__ __align__(16) __half Bs[128][40];

  const int tid = threadIdx.x;
  const int wave = tid >> 6, lane = tid & 63;
  const int wr = wave >> 2, wc = wave & 3;      // wave tile: 64 rows x 32 cols
  const int fr = lane & 15, kg = lane >> 4;

  v4f acc[4][2];
#pragma unroll
  for (int i = 0; i < 4; i++)
#pragma unroll
    for (int jj = 0; jj < 2; jj++) acc[i][jj] = (v4f)(0.f);

  const int lr = tid >> 2;          // load row 0..127
  const int lc = (tid & 3) * 8;     // k offset
  size_t abase;
  if (XL) {
    const int m = m0 + lr, t = m >> 5, bb = m & 31;
    abase = ((size_t)(bb * 512 + t)) * DK + lc;
  } else {
    abase = (size_t)(m0 + lr) * DK + lc;
  }
  const size_t bbase = (size_t)(n0 + lr) * DK + lc;

  for (int k0 = 0; k0 < DK; k0 += 32) {
    *(uint4*)&As[lr][lc] = *(const uint4*)(A + abase + k0);
    *(uint4*)&Bs[lr][lc] = *(const uint4*)(Wd + bbase + k0);
    __syncthreads();
    v8hf af[4], bf[2];
#pragma unroll
    for (int i = 0; i < 4; i++)
      af[i] = *(const v8hf*)&As[wr * 64 + i * 16 + fr][kg * 8];
#pragma unroll
    for (int jj = 0; jj < 2; jj++)
      bf[jj] = *(const v8hf*)&Bs[wc * 32 + jj * 16 + fr][kg * 8];
#pragma unroll
    for (int i = 0; i < 4; i++)
#pragma unroll
      for (int jj = 0; jj < 2; jj++)
        acc[i][jj] = __builtin_amdgcn_mfma_f32_16x16x32_f16(af[i], bf[jj], acc[i][jj], 0, 0, 0);
    __syncthreads();
  }

#pragma unroll
  for (int jj = 0; jj < 2; jj++) {
    const int n = n0 + wc * 32 + jj * 16 + fr;
    const float bv = bd[n];
#pragma unroll
    for (int i = 0; i < 4; i++) {
#pragma unroll
      for (int r = 0; r < 4; ++r) {
        const int m = m0 + wr * 64 + i * 16 + kg * 4 + r;
        out[(size_t)m * 1024 + n] = __float2half(acc[i][jj][r] + bv);
      }
    }
  }
}

// ---------------------------------------------------------------------------
// LSTM layer v14 (int8, readlane-h): one WG per (dir,batch) chain;
// block 512 = 8 waves. tid = gh*256 + j; thread owns gate rows (2gh, 2gh+1).
// h: ONE ds_read_b128 per thread (lanes 0..15 hold the 16 chunks) +
// v_readlane broadcasts -> wave-uniform dot operands. DS h-instrs 16 -> 1.
// W: chunks 0..7 LDS (128 KB, 16 b128/thread), chunks 8..15 plain invariant
// locals (reload-mode L2 stream, 128 KB/step). DS ~1900 cyc, stream ~1700.
// ---------------------------------------------------------------------------
__global__ __launch_bounds__(512, 1) void lstm_layer14(const uint4* __restrict__ WQ4,
                                                       const __half* __restrict__ xg,
                                                       const int* __restrict__ lens,
                                                       __half* __restrict__ out) {
  const int w = blockIdx.x, dir = w >> 5, b = w & 31;
  const int tid = threadIdx.x, gh = tid >> 8, j = tid & 255;
  const int lane = tid & 63;
  const int row0 = (2 * gh) * 256 + j;
  const int row1 = row0 + 256;

  __shared__ __align__(16) uint4 Wc[8 * 1024];   // 128 KB: chunks 0..7
  __shared__ __align__(16) uint4 hq4[2][16];     // 512 B (h int8, dbuf)
  __shared__ __align__(16) float aex[2][256];    // 2 KB

  const uint4* __restrict__ Wt = WQ4 + (size_t)dir * 16384;

  // stage chunks 0..7 into LDS (8192 uint4, 16 per thread)
#pragma unroll
  for (int i = 0; i < 16; ++i)
    Wc[i * 512 + tid] = Wt[i * 512 + tid];

  // chunks 8..15 as plain invariant locals (compiler reload-mode streams)
  uint4 sw0[8], sw1[8];
#pragma unroll
  for (int ch = 0; ch < 8; ++ch) {
    sw0[ch] = Wt[(size_t)(8 + ch) * 1024 + row0];
    sw1[ch] = Wt[(size_t)(8 + ch) * 1024 + row1];
  }

  if (tid < 64) ((unsigned int*)&hq4[0][0])[tid] = 0u;
  const int mylen = lens[b];
  float c = 0.f;

  const __half* xgb = xg + (size_t)dir * (512ull * 32 * 1024) + (size_t)b * 1024 + j;
  int tt = dir ? (mylen - 1) : 0;
  float p0, p1;
  {
    const __half* xr = xgb + (size_t)tt * (32 * 1024);
    p0 = __half2float(xr[(2 * gh) * 256]);
    p1 = __half2float(xr[(2 * gh + 1) * 256]);
  }
  __syncthreads();

#pragma unroll 1
  for (int t = 0; t < 512; ++t) {
    const int tcur = tt;
    // one wave-wide h read: lane c (c = lane&15) holds chunk c
    const uint4 hv4 = ((const uint4*)&hq4[t & 1][0])[lane & 15];

    int A0 = 0, B0 = 0, A1 = 0, B1 = 0;

    // LDS-resident chunks 0..7 (h via readlane -> wave-uniform operands)
#pragma unroll
    for (int ch = 0; ch < 8; ++ch) {
      const unsigned h0 = (unsigned)__builtin_amdgcn_readlane((int)hv4.x, ch);
      const unsigned h1 = (unsigned)__builtin_amdgcn_readlane((int)hv4.y, ch);
      const unsigned h2 = (unsigned)__builtin_amdgcn_readlane((int)hv4.z, ch);
      const unsigned h3 = (unsigned)__builtin_amdgcn_readlane((int)hv4.w, ch);
      const uint4 w0 = Wc[ch * 1024 + row0];
      const uint4 w1 = Wc[ch * 1024 + row1];
      A0 = sdot4_(w0.x, h0, A0); B0 = sdot4_(w0.y, h1, B0);
      A0 = sdot4_(w0.z, h2, A0); B0 = sdot4_(w0.w, h3, B0);
      A1 = sdot4_(w1.x, h0, A1); B1 = sdot4_(w1.y, h1, B1);
      A1 = sdot4_(w1.z, h2, A1); B1 = sdot4_(w1.w, h3, B1);
    }
    // streamed chunks 8..15
#pragma unroll
    for (int ch = 0; ch < 8; ++ch) {
      const unsigned h0 = (unsigned)__builtin_amdgcn_readlane((int)hv4.x, 8 + ch);
      const unsigned h1 = (unsigned)__builtin_amdgcn_readlane((int)hv4.y, 8 + ch);
      const unsigned h2 = (unsigned)__builtin_amdgcn_readlane((int)hv4.z, 8 + ch);
      const unsigned h3 = (unsigned)__builtin_amdgcn_readlane((int)hv4.w, 8 + ch);
      A0 = sdot4_(sw0[ch].x, h0, A0); B0 = sdot4_(sw0[ch].y, h1, B0);
      A0 = sdot4_(sw0[ch].z, h2, A0); B0 = sdot4_(sw0[ch].w, h3, B0);
      A1 = sdot4_(sw1[ch].x, h0, A1); B1 = sdot4_(sw1[ch].y, h1, B1);
      A1 = sdot4_(sw1[ch].z, h2, A1); B1 = sdot4_(sw1[ch].w, h3, B1);
    }

    const float sc = 3.844734e-6f;                 // 1/(2048*127)
    const float a0 = (float)(A0 + B0) * sc + p0;
    const float a1 = (float)(A1 + B1) * sc + p1;

    if (gh == 1) {                        // gates g, o -> pre-transform
      aex[0][j] = tanhf_(a0);
      aex[1][j] = sigmoidf_(a1);
    }
    __syncthreads();
    if (gh == 0) {                        // gates i, f + state update
      const float ig = sigmoidf_(a0);
      const float fg = sigmoidf_(a1);
      c = fg * c + ig * aex[0][j];
      const float hnew = aex[1][j] * tanhf_(c);
      out[((size_t)tcur * 32 + b) * 512 + dir * 256 + j] =
          __float2half((tcur < mylen) ? hnew : 0.f);
      ((signed char*)&hq4[(t + 1) & 1][0])[j] =
          (signed char)(int)rintf(hnew * 127.f);
    }
    if (t < 511) {
      const int tn = t + 1;
      tt = dir ? ((tn < mylen) ? (mylen - 1 - tn) : tn) : tn;
      const __half* xr = xgb + (size_t)tt * (32 * 1024);
      p0 = __half2float(xr[(2 * gh) * 256]);
      p1 = __half2float(xr[(2 * gh + 1) * 256]);
    }
    __syncthreads();
  }
}

// ---------------------------------------------------------------------------
// emit GEMM + fused row-softmax
// ---------------------------------------------------------------------------
__global__ __launch_bounds__(256) void emit_gemm(const __half* __restrict__ outA,
                                                 const __half* __restrict__ fcwh,
                                                 const float* __restrict__ fcb,
                                                 float* __restrict__ emit) {
  const int m0 = blockIdx.x * 64;
  __shared__ __align__(16) __half As[64][40];
  __shared__ __align__(16) __half Bs[64][40];

  const int tid = threadIdx.x;
  const int wave = tid >> 6, lane = tid & 63;
  const int fr = lane & 15, kg = lane >> 4;

  v4f acc[4];
#pragma unroll
  for (int i = 0; i < 4; i++) acc[i] = (v4f)(0.f);

  const int lr = tid >> 2;
  const int lc = (tid & 3) * 8;
  const size_t abase = (size_t)(m0 + lr) * 512 + lc;
  const size_t bbase = (size_t)lr * 512 + lc;

  for (int k0 = 0; k0 < 512; k0 += 32) {
    *(uint4*)&As[lr][lc] = *(const uint4*)(outA + abase + k0);
    *(uint4*)&Bs[lr][lc] = *(const uint4*)(fcwh + bbase + k0);
    __syncthreads();
    const v8hf af = *(const v8hf*)&As[wave * 16 + fr][kg * 8];
#pragma unroll
    for (int nb = 0; nb < 4; ++nb) {
      const v8hf bf = *(const v8hf*)&Bs[nb * 16 + fr][kg * 8];
      acc[nb] = __builtin_amdgcn_mfma_f32_16x16x32_f16(af, bf, acc[nb], 0, 0, 0);
    }
    __syncthreads();
  }

  float bv[4];
#pragma unroll
  for (int nb = 0; nb < 4; ++nb) bv[nb] = fcb[nb * 16 + fr];

#pragma unroll
  for (int r = 0; r < 4; ++r) {
    float v0 = acc[0][r] + bv[0], v1 = acc[1][r] + bv[1];
    float v2 = acc[2][r] + bv[2], v3 = acc[3][r] + bv[3];
    float mx = fmaxf(fmaxf(v0, v1), fmaxf(v2, v3));
#pragma unroll
    for (int off = 8; off; off >>= 1) mx = fmaxf(mx, __shfl_xor(mx, off));
    const float e0 = __expf(v0 - mx), e1 = __expf(v1 - mx);
    const float e2 = __expf(v2 - mx), e3 = __expf(v3 - mx);
    float sm = (e0 + e1) + (e2 + e3);
#pragma unroll
    for (int off = 8; off; off >>= 1) sm += __shfl_xor(sm, off);
    const float rinv = 1.f / sm;
    const int mrow = m0 + wave * 16 + kg * 4 + r;
    const int bb = mrow & 31, ttt = mrow >> 5;
    float* ep = emit + ((size_t)bb * 512 + ttt) * 64;
    ep[0 * 16 + fr] = e0 * rinv;
    ep[1 * 16 + fr] = e1 * rinv;
    ep[2 * 16 + fr] = e2 * rinv;
    ep[3 * 16 + fr] = e3 * rinv;
  }
}

__global__ __launch_bounds__(256) void score_kernel(const float* __restrict__ emit,
                                                    const float* __restrict__ trans,
                                                    const int* __restrict__ tags,
                                                    const int* __restrict__ lens,
                                                    float* __restrict__ total) {
  const int b = blockIdx.x;
  const int len = lens[b];
  float part = 0.f;
  for (int t = threadIdx.x; t < len; t += 256) {
    const int tg = tags[b * Ll + t];
    float v = emit[((size_t)b * Ll + t) * Ee + tg];
    if (t >= 1) v += trans[tags[b * Ll + t - 1] * Ee + tg];
    part += v;
  }
  for (int off = 32; off; off >>= 1) part += __shfl_xor(part, off);
  __shared__ float wsum[4];
  if ((threadIdx.x & 63) == 0) wsum[threadIdx.x >> 6] = part;
  __syncthreads();
  if (threadIdx.x == 0) total[b] = wsum[0] + wsum[1] + wsum[2] + wsum[3];
}

// ---------------------------------------------------------------------------
// CRF prep: cm[j] = max_k trans[k][j]; E[j][k] = exp(trans[k][j] - cm[j])
// ---------------------------------------------------------------------------
__global__ __launch_bounds__(64) void crf_prep(const float* __restrict__ trans,
                                               float* __restrict__ E,
                                               float* __restrict__ cm) {
  const int j = threadIdx.x;
  float m = -1e30f;
  for (int k = 0; k < 64; k++) m = fmaxf(m, trans[k * 64 + j]);
  cm[j] = m;
  for (int k = 0; k < 64; k++) E[j * 64 + k] = __expf(trans[k * 64 + j] - m);
}

// ---------------------------------------------------------------------------
// CRF scan v2 (factorized): d_new[j] = log(sum_k e_k * E[j][k]) + maxd + cm[j]
// ---------------------------------------------------------------------------
__global__ __launch_bounds__(64) void crf_scan2(const float* __restrict__ emit,
                                                const float* __restrict__ E,
                                                const float* __restrict__ cm,
                                                const int* __restrict__ lens,
                                                float* __restrict__ dout) {
  const int b = blockIdx.x, j = threadIdx.x;
  __shared__ float el[2][64];
  float Er[64];
#pragma unroll
  for (int kc = 0; kc < 16; ++kc) {
    const float4 v = *(const float4*)(E + j * 64 + 4 * kc);
    Er[4 * kc + 0] = v.x; Er[4 * kc + 1] = v.y;
    Er[4 * kc + 2] = v.z; Er[4 * kc + 3] = v.w;
  }
  const float cmj = cm[j];
  const int len = lens[b];
  const float* eb = emit + (size_t)b * 512 * 64 + j;
  float d = eb[0];
  float enext = (len > 1) ? eb[64] : 0.f;

  for (int t = 1; t < len; ++t) {
    float m = d;
#pragma unroll
    for (int off = 32; off; off >>= 1) m = fmaxf(m, __shfl_xor(m, off));
    const float ej = __expf(d - m);
    el[t & 1][j] = ej;
    const float emt = enext;
    if (t + 1 < len) enext = eb[(size_t)(t + 1) * 64];
    __syncthreads();
    float s0 = 0.f, s1 = 0.f, s2 = 0.f, s3 = 0.f;
    const float4* e4 = (const float4*)&el[t & 1][0];
#pragma unroll
    for (int kc = 0; kc < 16; ++kc) {
      const float4 ev = e4[kc];
      s0 = fmaf(ev.x, Er[4 * kc + 0], s0);
      s1 = fmaf(ev.y, Er[4 * kc + 1], s1);
      s2 = fmaf(ev.z, Er[4 * kc + 2], s2);
      s3 = fmaf(ev.w, Er[4 * kc + 3], s3);
    }
    d = __logf((s0 + s1) + (s2 + s3)) + m + cmj + emt;
    __syncthreads();
  }
  dout[b * 64 + j] = d;
}

__global__ __launch_bounds__(64) void final_kernel(const float* __restrict__ dbuf,
                                                   const float* __restrict__ total,
                                                   const int* __restrict__ lens,
                                                   float* __restrict__ out) {
  const int j = threadIdx.x;
  float lsum = 0.f;
  for (int b = 0; b < 32; b++) {
    const float d = dbuf[b * 64 + j];
    float m = d;
    for (int off = 32; off; off >>= 1) m = fmaxf(m, __shfl_xor(m, off));
    const float e = __expf(d - m);
    float s = e;
    for (int off = 32; off; off >>= 1) s += __shfl_xor(s, off);
    const float Z = __logf(s) + m;
    if (j == 0) lsum += -(total[b] - Z) / (float)lens[b];
  }
  if (j == 0) out[0] = lsum / 32.f;
}

// ---------------------------------------------------------------------------
extern "C" void kernel_launch(void* const* d_in, const int* in_sizes, int n_in,
                              void* d_out, int out_size, void* d_ws, size_t ws_size,
                              hipStream_t stream) {
  const float* x = (const float*)d_in[0];
  const int* lens = (const int*)d_in[1];
  const int* tags = (const int*)d_in[2];
  const float* w_ih_l0 = (const float*)d_in[4];
  const float* w_hh_l0 = (const float*)d_in[5];
  const float* b_l0 = (const float*)d_in[6];
  const float* w_ih_l12 = (const float*)d_in[7];
  const float* w_hh_l12 = (const float*)d_in[8];
  const float* b_l12 = (const float*)d_in[9];
  const float* fc_w = (const float*)d_in[10];
  const float* fc_b = (const float*)d_in[11];
  const float* trans = (const float*)d_in[12];

  char* ws = (char*)d_ws;
  __half* xg = (__half*)ws;                          // 64 MiB
  __half* xh = (__half*)(ws + 67108864);             // 32 MiB
  __half* outA = (__half*)(ws + 100663296);          // 16 MiB
  __half* outB = (__half*)(ws + 117440512);          // 16 MiB
  uint4* WQ4 = (uint4*)(ws + 134217728);             // 1.5 MiB (whh int8, chunk layout)
  __half* WIH0 = (__half*)(ws + 137363456);          // 4 MiB
  __half* WIH12 = (__half*)(ws + 141557760);         // 4 MiB
  float* Ebuf = (float*)(ws + 145752064);            // 16 KiB
  float* cmbuf = (float*)(ws + 145768448);           // 256 B
  __half* fcwh = (__half*)(ws + 145768960);          // 64 KiB
  // CRF buffers alias the (dead-by-then) xg region
  float* emit = (float*)ws;                          // 4 MiB
  float* total = (float*)(ws + 4194304);
  float* dbuf = total + 32;

  // one-time conversions + CRF prep
  cvt_h<<<8192, 256, 0, stream>>>(x, xh, 2097152);
  cvt_h<<<1024, 256, 0, stream>>>(w_ih_l0, WIH0, 262144);
  cvt_h<<<1024, 256, 0, stream>>>(w_ih_l12, WIH12, 262144);
  cvt_h<<<16, 256, 0, stream>>>(fc_w, fcwh, 4096);
  conv_wq4<<<dim3(64, 2), 256, 0, stream>>>(w_hh_l0, WQ4);
  conv_wq4<<<dim3(64, 4), 256, 0, stream>>>(w_hh_l12, WQ4 + 2 * 16384);
  crf_prep<<<1, 64, 0, stream>>>(trans, Ebuf, cmbuf);

  const dim3 ggrid(16, 128);

  // layer 0
  xg_gemm2<1024, true><<<ggrid, 512, 0, stream>>>(xh, WIH0, b_l0, xg);
  lstm_layer14<<<64, 512, 0, stream>>>(WQ4, xg, lens, outA);

  // layer 1
  xg_gemm2<512, false><<<ggrid, 512, 0, stream>>>(outA, WIH12, b_l12, xg);
  lstm_layer14<<<64, 512, 0, stream>>>(WQ4 + 2 * 16384, xg, lens, outB);

  // layer 2
  xg_gemm2<512, false><<<ggrid, 512, 0, stream>>>(outB, WIH12 + 2 * 1024 * 512,
                                                  b_l12 + 2 * 1024, xg);
  lstm_layer14<<<64, 512, 0, stream>>>(WQ4 + 4 * 16384, xg, lens, outA);

  // CRF
  emit_gemm<<<256, 256, 0, stream>>>(outA, fcwh, fc_b, emit);
  score_kernel<<<Bb, 256, 0, stream>>>(emit, trans, tags, lens, total);
  crf_scan2<<<Bb, 64, 0, stream>>>(emit, Ebuf, cmbuf, lens, dbuf);
  final_kernel<<<1, 64, 0, stream>>>(dbuf, total, lens, (float*)d_out);
}

// Round 15
// 2060.861 us; speedup vs baseline: 1.3515x; 1.3515x over previous
//
#include <hip/hip_runtime.h>
#include <hip/hip_fp16.h>

#define Bb 32
#define Ll 512
#define Dd 1024
#define Hh 256
#define Ee 64

__device__ __forceinline__ float sigmoidf_(float x) { return 1.f / (1.f + __expf(-x)); }
__device__ __forceinline__ float tanhf_(float x) { return 1.f - 2.f / (__expf(2.f * x) + 1.f); }

typedef _Float16 v8hf __attribute__((ext_vector_type(8)));
typedef float v4f __attribute__((ext_vector_type(4)));

__device__ __forceinline__ int sdot8_(unsigned int a, unsigned int b, int acc) {
#if __has_builtin(__builtin_amdgcn_sdot8)
  return __builtin_amdgcn_sdot8((int)a, (int)b, acc, false);
#else
  int r = acc;
#pragma unroll
  for (int i = 0; i < 8; i++)
    r += (((int)(a << (28 - 4 * i))) >> 28) * (((int)(b << (28 - 4 * i))) >> 28);
  return r;
#endif
}

// 32 int4 MACs (one uint4 pair) split over two accumulators
__device__ __forceinline__ void dot8c(uint4 wv, uint4 hv, int& a, int& b) {
  a = sdot8_(wv.x, hv.x, a);
  b = sdot8_(wv.y, hv.y, b);
  a = sdot8_(wv.z, hv.z, a);
  b = sdot8_(wv.w, hv.w, b);
}

// ---------------------------------------------------------------------------
// generic f32 -> f16 converter (8 elems/thread)
// ---------------------------------------------------------------------------
__global__ __launch_bounds__(256) void cvt_h(const float* __restrict__ s,
                                             __half* __restrict__ d, int n8) {
  const int i = blockIdx.x * 256 + threadIdx.x;
  if (i >= n8) return;
  const float4 a = ((const float4*)s)[2 * i];
  const float4 b = ((const float4*)s)[2 * i + 1];
  union { __half h[8]; uint4 u; } o;
  o.h[0] = __float2half(a.x); o.h[1] = __float2half(a.y);
  o.h[2] = __float2half(a.z); o.h[3] = __float2half(a.w);
  o.h[4] = __float2half(b.x); o.h[5] = __float2half(b.y);
  o.h[6] = __float2half(b.z); o.h[7] = __float2half(b.w);
  ((uint4*)d)[i] = o.u;
}

// ---------------------------------------------------------------------------
// W_hh -> int4, 32-k-chunk layout: WQ2[slice][ch(8)][row(1024)] uint4
// q = clamp(round(w * 112), -7, 7); nibble i of dword = k-element i.
// ---------------------------------------------------------------------------
__global__ __launch_bounds__(256) void conv_wq2(const float* __restrict__ src,
                                                uint4* __restrict__ dst) {
  const int s = blockIdx.y;
  const int idx = blockIdx.x * 256 + threadIdx.x;   // 0..8191
  const int row = idx & 1023;
  const int ch = idx >> 10;                          // 0..7
  const float* sp = src + (size_t)s * 262144 + (size_t)row * 256 + ch * 32;
  unsigned int u[4];
#pragma unroll
  for (int d = 0; d < 4; ++d) {
    unsigned int dw = 0;
#pragma unroll
    for (int n = 0; n < 8; ++n) {
      int q = (int)rintf(sp[d * 8 + n] * 112.f);
      q = max(-7, min(7, q));
      dw |= ((unsigned int)(q & 0xF)) << (4 * n);
    }
    u[d] = dw;
  }
  dst[(size_t)s * 8192 + (size_t)ch * 1024 + row] = make_uint4(u[0], u[1], u[2], u[3]);
}

// ---------------------------------------------------------------------------
// MFMA f16 GEMM v2: 128x128 tile, 512 thr / 8 waves (2x4), padded LDS.
// ---------------------------------------------------------------------------
template <int DK, bool XL>
__global__ __launch_bounds__(512) void xg_gemm2(const __half* __restrict__ A,
                                                const __half* __restrict__ W,
                                                const float* __restrict__ bias,
                                                __half* __restrict__ xg) {
  const int dir = blockIdx.x >> 3;
  const int n0 = (blockIdx.x & 7) * 128;
  const int m0 = blockIdx.y * 128;
  const __half* Wd = W + (size_t)dir * (1024 * DK);
  const float* bd = bias + dir * 1024;
  __half* out = xg + (size_t)dir * (16384ull * 1024);

  __shared__ __align__(16) __half As[128][40];
  __shared__ __align__(16) __half Bs[128][40];

  const int tid = threadIdx.x;
  const int wave = tid >> 6, lane = tid & 63;
  const int wr = wave >> 2, wc = wave & 3;      // wave tile: 64 rows x 32 cols
  const int fr = lane & 15, kg = lane >> 4;

  v4f acc[4][2];
#pragma unroll
  for (int i = 0; i < 4; i++)
#pragma unroll
    for (int jj = 0; jj < 2; jj++) acc[i][jj] = (v4f)(0.f);

  const int lr = tid >> 2;          // load row 0..127
  const int lc = (tid & 3) * 8;     // k offset
  size_t abase;
  if (XL) {
    const int m = m0 + lr, t = m >> 5, bb = m & 31;
    abase = ((size_t)(bb * 512 + t)) * DK + lc;
  } else {
    abase = (size_t)(m0 + lr) * DK + lc;
  }
  const size_t bbase = (size_t)(n0 + lr) * DK + lc;

  for (int k0 = 0; k0 < DK; k0 += 32) {
    *(uint4*)&As[lr][lc] = *(const uint4*)(A + abase + k0);
    *(uint4*)&Bs[lr][lc] = *(const uint4*)(Wd + bbase + k0);
    __syncthreads();
    v8hf af[4], bf[2];
#pragma unroll
    for (int i = 0; i < 4; i++)
      af[i] = *(const v8hf*)&As[wr * 64 + i * 16 + fr][kg * 8];
#pragma unroll
    for (int jj = 0; jj < 2; jj++)
      bf[jj] = *(const v8hf*)&Bs[wc * 32 + jj * 16 + fr][kg * 8];
#pragma unroll
    for (int i = 0; i < 4; i++)
#pragma unroll
      for (int jj = 0; jj < 2; jj++)
        acc[i][jj] = __builtin_amdgcn_mfma_f32_16x16x32_f16(af[i], bf[jj], acc[i][jj], 0, 0, 0);
    __syncthreads();
  }

#pragma unroll
  for (int jj = 0; jj < 2; jj++) {
    const int n = n0 + wc * 32 + jj * 16 + fr;
    const float bv = bd[n];
#pragma unroll
    for (int i = 0; i < 4; i++) {
#pragma unroll
      for (int r = 0; r < 4; ++r) {
        const int m = m0 + wr * 64 + i * 16 + kg * 4 + r;
        out[(size_t)m * 1024 + n] = __float2half(acc[i][jj][r] + bv);
      }
    }
  }
}

// ---------------------------------------------------------------------------
// LSTM layer v15 (int4, dot8): one WG per (dir,batch) chain; block 512.
// tid = gh*256 + j; thread owns gate rows (2gh, 2gh+1), full K=256 dot each.
// W int4 (scale 112), 8 chunks of K=32: chunks 0..1 LDS (32 KB), 2..7 plain
// invariant locals (reload-mode L2 stream, 96 KB/step). h int4 (scale 7)
// packed 128 B, double-buffered in LDS: 8 b128 broadcasts/thread.
// DS ~1440 cyc, stream ~1230, VALU ~1400: balanced.
// ---------------------------------------------------------------------------
__global__ __launch_bounds__(512, 1) void lstm_layer15(const uint4* __restrict__ WQ2,
                                                       const __half* __restrict__ xg,
                                                       const int* __restrict__ lens,
                                                       __half* __restrict__ out) {
  const int w = blockIdx.x, dir = w >> 5, b = w & 31;
  const int tid = threadIdx.x, gh = tid >> 8, j = tid & 255;
  const int row0 = (2 * gh) * 256 + j;
  const int row1 = row0 + 256;

  __shared__ __align__(16) uint4 Wc[2 * 1024];   // 32 KB: chunks 0..1
  __shared__ __align__(16) uint4 hq4[2][8];      // 256 B (h int4, dbuf)
  __shared__ __align__(16) float aex[2][256];    // 2 KB

  const uint4* __restrict__ Wt = WQ2 + (size_t)dir * 8192;

  // stage chunks 0..1 into LDS (2048 uint4, 4 per thread)
#pragma unroll
  for (int i = 0; i < 4; ++i)
    Wc[i * 512 + tid] = Wt[i * 512 + tid];

  // chunks 2..7 as plain invariant locals (compiler reload-mode streams)
  uint4 sw0[6], sw1[6];
#pragma unroll
  for (int ch = 0; ch < 6; ++ch) {
    sw0[ch] = Wt[(size_t)(2 + ch) * 1024 + row0];
    sw1[ch] = Wt[(size_t)(2 + ch) * 1024 + row1];
  }

  if (tid < 32) ((unsigned int*)&hq4[0][0])[tid] = 0u;
  const int mylen = lens[b];
  float c = 0.f;

  const __half* xgb = xg + (size_t)dir * (512ull * 32 * 1024) + (size_t)b * 1024 + j;
  int tt = dir ? (mylen - 1) : 0;
  float p0, p1;
  {
    const __half* xr = xgb + (size_t)tt * (32 * 1024);
    p0 = __half2float(xr[(2 * gh) * 256]);
    p1 = __half2float(xr[(2 * gh + 1) * 256]);
  }
  __syncthreads();

#pragma unroll 1
  for (int t = 0; t < 512; ++t) {
    const int tcur = tt;
    const uint4* hp = &hq4[t & 1][0];
    int A0 = 0, B0 = 0, A1 = 0, B1 = 0;

    // LDS-resident chunks 0..1
#pragma unroll
    for (int ch = 0; ch < 2; ++ch) {
      const uint4 hv = hp[ch];
      dot8c(Wc[ch * 1024 + row0], hv, A0, B0);
      dot8c(Wc[ch * 1024 + row1], hv, A1, B1);
    }
    // streamed chunks 2..7
#pragma unroll
    for (int ch = 0; ch < 6; ++ch) {
      const uint4 hv = hp[2 + ch];
      dot8c(sw0[ch], hv, A0, B0);
      dot8c(sw1[ch], hv, A1, B1);
    }

    const float sc = 1.2755102e-3f;                // 1/(112*7)
    const float a0 = (float)(A0 + B0) * sc + p0;
    const float a1 = (float)(A1 + B1) * sc + p1;

    if (gh == 1) {                        // gates g, o -> pre-transform
      aex[0][j] = tanhf_(a0);
      aex[1][j] = sigmoidf_(a1);
    }
    __syncthreads();
    if (gh == 0) {                        // gates i, f + state update
      const float ig = sigmoidf_(a0);
      const float fg = sigmoidf_(a1);
      c = fg * c + ig * aex[0][j];
      const float hnew = aex[1][j] * tanhf_(c);
      out[((size_t)tcur * 32 + b) * 512 + dir * 256 + j] =
          __float2half((tcur < mylen) ? hnew : 0.f);
      // pack h -> int4 (scale 7): even j writes byte (j/2)
      const int q = (int)rintf(hnew * 7.f);
      const int pk = __shfl_xor(q, 1);
      if ((j & 1) == 0)
        ((unsigned char*)&hq4[(t + 1) & 1][0])[j >> 1] =
            (unsigned char)((q & 0xF) | ((pk & 0xF) << 4));
    }
    if (t < 511) {
      const int tn = t + 1;
      tt = dir ? ((tn < mylen) ? (mylen - 1 - tn) : tn) : tn;
      const __half* xr = xgb + (size_t)tt * (32 * 1024);
      p0 = __half2float(xr[(2 * gh) * 256]);
      p1 = __half2float(xr[(2 * gh + 1) * 256]);
    }
    __syncthreads();
  }
}

// ---------------------------------------------------------------------------
// emit GEMM + fused row-softmax
// ---------------------------------------------------------------------------
__global__ __launch_bounds__(256) void emit_gemm(const __half* __restrict__ outA,
                                                 const __half* __restrict__ fcwh,
                                                 const float* __restrict__ fcb,
                                                 float* __restrict__ emit) {
  const int m0 = blockIdx.x * 64;
  __shared__ __align__(16) __half As[64][40];
  __shared__ __align__(16) __half Bs[64][40];

  const int tid = threadIdx.x;
  const int wave = tid >> 6, lane = tid & 63;
  const int fr = lane & 15, kg = lane >> 4;

  v4f acc[4];
#pragma unroll
  for (int i = 0; i < 4; i++) acc[i] = (v4f)(0.f);

  const int lr = tid >> 2;
  const int lc = (tid & 3) * 8;
  const size_t abase = (size_t)(m0 + lr) * 512 + lc;
  const size_t bbase = (size_t)lr * 512 + lc;

  for (int k0 = 0; k0 < 512; k0 += 32) {
    *(uint4*)&As[lr][lc] = *(const uint4*)(outA + abase + k0);
    *(uint4*)&Bs[lr][lc] = *(const uint4*)(fcwh + bbase + k0);
    __syncthreads();
    const v8hf af = *(const v8hf*)&As[wave * 16 + fr][kg * 8];
#pragma unroll
    for (int nb = 0; nb < 4; ++nb) {
      const v8hf bf = *(const v8hf*)&Bs[nb * 16 + fr][kg * 8];
      acc[nb] = __builtin_amdgcn_mfma_f32_16x16x32_f16(af, bf, acc[nb], 0, 0, 0);
    }
    __syncthreads();
  }

  float bv[4];
#pragma unroll
  for (int nb = 0; nb < 4; ++nb) bv[nb] = fcb[nb * 16 + fr];

#pragma unroll
  for (int r = 0; r < 4; ++r) {
    float v0 = acc[0][r] + bv[0], v1 = acc[1][r] + bv[1];
    float v2 = acc[2][r] + bv[2], v3 = acc[3][r] + bv[3];
    float mx = fmaxf(fmaxf(v0, v1), fmaxf(v2, v3));
#pragma unroll
    for (int off = 8; off; off >>= 1) mx = fmaxf(mx, __shfl_xor(mx, off));
    const float e0 = __expf(v0 - mx), e1 = __expf(v1 - mx);
    const float e2 = __expf(v2 - mx), e3 = __expf(v3 - mx);
    float sm = (e0 + e1) + (e2 + e3);
#pragma unroll
    for (int off = 8; off; off >>= 1) sm += __shfl_xor(sm, off);
    const float rinv = 1.f / sm;
    const int mrow = m0 + wave * 16 + kg * 4 + r;
    const int bb = mrow & 31, ttt = mrow >> 5;
    float* ep = emit + ((size_t)bb * 512 + ttt) * 64;
    ep[0 * 16 + fr] = e0 * rinv;
    ep[1 * 16 + fr] = e1 * rinv;
    ep[2 * 16 + fr] = e2 * rinv;
    ep[3 * 16 + fr] = e3 * rinv;
  }
}

__global__ __launch_bounds__(256) void score_kernel(const float* __restrict__ emit,
                                                    const float* __restrict__ trans,
                                                    const int* __restrict__ tags,
                                                    const int* __restrict__ lens,
                                                    float* __restrict__ total) {
  const int b = blockIdx.x;
  const int len = lens[b];
  float part = 0.f;
  for (int t = threadIdx.x; t < len; t += 256) {
    const int tg = tags[b * Ll + t];
    float v = emit[((size_t)b * Ll + t) * Ee + tg];
    if (t >= 1) v += trans[tags[b * Ll + t - 1] * Ee + tg];
    part += v;
  }
  for (int off = 32; off; off >>= 1) part += __shfl_xor(part, off);
  __shared__ float wsum[4];
  if ((threadIdx.x & 63) == 0) wsum[threadIdx.x >> 6] = part;
  __syncthreads();
  if (threadIdx.x == 0) total[b] = wsum[0] + wsum[1] + wsum[2] + wsum[3];
}

// ---------------------------------------------------------------------------
// CRF prep: cm[j] = max_k trans[k][j]; E[j][k] = exp(trans[k][j] - cm[j])
// ---------------------------------------------------------------------------
__global__ __launch_bounds__(64) void crf_prep(const float* __restrict__ trans,
                                               float* __restrict__ E,
                                               float* __restrict__ cm) {
  const int j = threadIdx.x;
  float m = -1e30f;
  for (int k = 0; k < 64; k++) m = fmaxf(m, trans[k * 64 + j]);
  cm[j] = m;
  for (int k = 0; k < 64; k++) E[j * 64 + k] = __expf(trans[k * 64 + j] - m);
}

// ---------------------------------------------------------------------------
// CRF scan v2 (factorized): d_new[j] = log(sum_k e_k * E[j][k]) + maxd + cm[j]
// ---------------------------------------------------------------------------
__global__ __launch_bounds__(64) void crf_scan2(const float* __restrict__ emit,
                                                const float* __restrict__ E,
                                                const float* __restrict__ cm,
                                                const int* __restrict__ lens,
                                                float* __restrict__ dout) {
  const int b = blockIdx.x, j = threadIdx.x;
  __shared__ float el[2][64];
  float Er[64];
#pragma unroll
  for (int kc = 0; kc < 16; ++kc) {
    const float4 v = *(const float4*)(E + j * 64 + 4 * kc);
    Er[4 * kc + 0] = v.x; Er[4 * kc + 1] = v.y;
    Er[4 * kc + 2] = v.z; Er[4 * kc + 3] = v.w;
  }
  const float cmj = cm[j];
  const int len = lens[b];
  const float* eb = emit + (size_t)b * 512 * 64 + j;
  float d = eb[0];
  float enext = (len > 1) ? eb[64] : 0.f;

  for (int t = 1; t < len; ++t) {
    float m = d;
#pragma unroll
    for (int off = 32; off; off >>= 1) m = fmaxf(m, __shfl_xor(m, off));
    const float ej = __expf(d - m);
    el[t & 1][j] = ej;
    const float emt = enext;
    if (t + 1 < len) enext = eb[(size_t)(t + 1) * 64];
    __syncthreads();
    float s0 = 0.f, s1 = 0.f, s2 = 0.f, s3 = 0.f;
    const float4* e4 = (const float4*)&el[t & 1][0];
#pragma unroll
    for (int kc = 0; kc < 16; ++kc) {
      const float4 ev = e4[kc];
      s0 = fmaf(ev.x, Er[4 * kc + 0], s0);
      s1 = fmaf(ev.y, Er[4 * kc + 1], s1);
      s2 = fmaf(ev.z, Er[4 * kc + 2], s2);
      s3 = fmaf(ev.w, Er[4 * kc + 3], s3);
    }
    d = __logf((s0 + s1) + (s2 + s3)) + m + cmj + emt;
    __syncthreads();
  }
  dout[b * 64 + j] = d;
}

__global__ __launch_bounds__(64) void final_kernel(const float* __restrict__ dbuf,
                                                   const float* __restrict__ total,
                                                   const int* __restrict__ lens,
                                                   float* __restrict__ out) {
  const int j = threadIdx.x;
  float lsum = 0.f;
  for (int b = 0; b < 32; b++) {
    const float d = dbuf[b * 64 + j];
    float m = d;
    for (int off = 32; off; off >>= 1) m = fmaxf(m, __shfl_xor(m, off));
    const float e = __expf(d - m);
    float s = e;
    for (int off = 32; off; off >>= 1) s += __shfl_xor(s, off);
    const float Z = __logf(s) + m;
    if (j == 0) lsum += -(total[b] - Z) / (float)lens[b];
  }
  if (j == 0) out[0] = lsum / 32.f;
}

// ---------------------------------------------------------------------------
extern "C" void kernel_launch(void* const* d_in, const int* in_sizes, int n_in,
                              void* d_out, int out_size, void* d_ws, size_t ws_size,
                              hipStream_t stream) {
  const float* x = (const float*)d_in[0];
  const int* lens = (const int*)d_in[1];
  const int* tags = (const int*)d_in[2];
  const float* w_ih_l0 = (const float*)d_in[4];
  const float* w_hh_l0 = (const float*)d_in[5];
  const float* b_l0 = (const float*)d_in[6];
  const float* w_ih_l12 = (const float*)d_in[7];
  const float* w_hh_l12 = (const float*)d_in[8];
  const float* b_l12 = (const float*)d_in[9];
  const float* fc_w = (const float*)d_in[10];
  const float* fc_b = (const float*)d_in[11];
  const float* trans = (const float*)d_in[12];

  char* ws = (char*)d_ws;
  __half* xg = (__half*)ws;                          // 64 MiB
  __half* xh = (__half*)(ws + 67108864);             // 32 MiB
  __half* outA = (__half*)(ws + 100663296);          // 16 MiB
  __half* outB = (__half*)(ws + 117440512);          // 16 MiB
  uint4* WQ2 = (uint4*)(ws + 134217728);             // 768 KiB (whh int4, chunk32)
  __half* WIH0 = (__half*)(ws + 137363456);          // 4 MiB
  __half* WIH12 = (__half*)(ws + 141557760);         // 4 MiB
  float* Ebuf = (float*)(ws + 145752064);            // 16 KiB
  float* cmbuf = (float*)(ws + 145768448);           // 256 B
  __half* fcwh = (__half*)(ws + 145768960);          // 64 KiB
  // CRF buffers alias the (dead-by-then) xg region
  float* emit = (float*)ws;                          // 4 MiB
  float* total = (float*)(ws + 4194304);
  float* dbuf = total + 32;

  // one-time conversions + CRF prep
  cvt_h<<<8192, 256, 0, stream>>>(x, xh, 2097152);
  cvt_h<<<1024, 256, 0, stream>>>(w_ih_l0, WIH0, 262144);
  cvt_h<<<1024, 256, 0, stream>>>(w_ih_l12, WIH12, 262144);
  cvt_h<<<16, 256, 0, stream>>>(fc_w, fcwh, 4096);
  conv_wq2<<<dim3(32, 2), 256, 0, stream>>>(w_hh_l0, WQ2);
  conv_wq2<<<dim3(32, 4), 256, 0, stream>>>(w_hh_l12, WQ2 + 2 * 8192);
  crf_prep<<<1, 64, 0, stream>>>(trans, Ebuf, cmbuf);

  const dim3 ggrid(16, 128);

  // layer 0
  xg_gemm2<1024, true><<<ggrid, 512, 0, stream>>>(xh, WIH0, b_l0, xg);
  lstm_layer15<<<64, 512, 0, stream>>>(WQ2, xg, lens, outA);

  // layer 1
  xg_gemm2<512, false><<<ggrid, 512, 0, stream>>>(outA, WIH12, b_l12, xg);
  lstm_layer15<<<64, 512, 0, stream>>>(WQ2 + 2 * 8192, xg, lens, outB);

  // layer 2
  xg_gemm2<512, false><<<ggrid, 512, 0, stream>>>(outB, WIH12 + 2 * 1024 * 512,
                                                  b_l12 + 2 * 1024, xg);
  lstm_layer15<<<64, 512, 0, stream>>>(WQ2 + 4 * 8192, xg, lens, outA);

  // CRF
  emit_gemm<<<256, 256, 0, stream>>>(outA, fcwh, fc_b, emit);
  score_kernel<<<Bb, 256, 0, stream>>>(emit, trans, tags, lens, total);
  crf_scan2<<<Bb, 64, 0, stream>>>(emit, Ebuf, cmbuf, lens, dbuf);
  final_kernel<<<1, 64, 0, stream>>>(dbuf, total, lens, (float*)d_out);
}